// Round 1
// 188.927 us; speedup vs baseline: 1.0364x; 1.0364x over previous
//
#include <hip/hip_runtime.h>
#include <hip/hip_bf16.h>

// Problem: B=512, N_SLOTS=128, IN=2048, MEM=64, OUT=2048.
// Dtype self-detection: each wave ballots on x's bit patterns (fp32 buffers
// holding bf16-quantized values, per R4-R7 evidence; bf16 world also handled).
// Pipeline (4 dispatches): k_pack (bf16-pack A/x, Wo^T, proj weights, biases,
// + NEW: transposed bf16 W_r-mem/W_pr/W_f-tail panel) -> k_proj_dot (px) ->
// k_fused (NOW MFMA-based: one [128x64]@[64x80] per batch computes active/
// passive scores, forget, and the full remember matrix in one shot; softmax
// via wave shuffles; epilogue writes recalls into A's tail + gated update)
// -> k_gemm (barrier-free wave-tiled MFMA).
// d_out = [output (512*2048) | new_memory (512*128*64)], input dtype.

#define NB    512
#define NSLOT 128
#define DIN   2048
#define DMEM  64
#define DOUT  2048
#define PXW   130              // 64 (q) + 1 (forget) + 65 (remember)
#define KT    (DIN + 2 * DMEM) // 2176 = GEMM K and packed row stride
#define NK    (KT / 32)        // 68
#define MS    72               // mem_bf / Bp row stride in bf16 (72*2B: 2-way-free banks)
#define OS    68               // out_s row stride in f32

typedef __hip_bfloat16 bf16;
typedef __attribute__((ext_vector_type(8))) short short8;
typedef __attribute__((ext_vector_type(4))) float f32x4;

template<bool BF16>
__device__ __forceinline__ float ld(const void* p, size_t i) {
  if (BF16) return __bfloat162float(((const bf16*)p)[i]);
  return ((const float*)p)[i];
}
template<bool BF16>
__device__ __forceinline__ void st(void* p, size_t i, float v) {
  if (BF16) ((bf16*)p)[i] = __float2bfloat16(v);
  else      ((float*)p)[i] = v;
}
// f32 -> bf16 bits (RNE); bf16 bits -> f32 (exact).
__device__ __forceinline__ unsigned short f2bu(float f) {
  unsigned int u = __builtin_bit_cast(unsigned int, f);
  u = (u + 0x7FFFu + ((u >> 16) & 1u)) >> 16;
  return (unsigned short)u;
}
__device__ __forceinline__ float bu2f(unsigned short u) {
  unsigned int w = ((unsigned int)u) << 16;
  return __builtin_bit_cast(float, w);
}

// Wave-level dtype detect: sample 64 even uint16 positions of x. bf16 data ->
// sane exponents (~100% of N(0,1)); f32 data -> even positions are mantissa
// low-halves (~16% sane). All waves sample identical addresses -> identical
// verdict everywhere, every launch (x is pristine-restored).
__device__ __forceinline__ bool detect_bf16(const void* x) {
  const unsigned short* u = (const unsigned short*)x;
  int lane = threadIdx.x & 63;
  unsigned short v = u[lane * 2048];
  int e = (v >> 7) & 0xFF;
  unsigned long long m = __ballot(e >= 100 && e <= 140);
  return __popcll(m) > 32;
}

union U8x16 { uint4 v; unsigned short u[8]; };

// ---------------------------------------------------------------------------
// k_pack: one dispatch, block ranges:
//  [0,1088)   : Bt[n][k] = Wo[k][n] bf16   (34 k-tiles x 32 n-tiles, LDS transpose)
//  [1088,1216): Abf[b][0:2048] = x bf16    (4 rows/block)
//  [1216,1280): Wt[j][k] = proj-weight col j (LDS transpose, 65-col halves)
//  [1280,1288): bias_o[2048] f32
//  [1288]     : bias_px[130] f32
//  [1289]     : Wrm[c][k] = W_r[2048+k][c] bf16 (65x64), wprb/wfmb bf16[64]
// ---------------------------------------------------------------------------
template<bool BF16>
__device__ void pack_body(
    const void* x, const void* W_ar, const void* W_pr, const void* W_f,
    const void* W_r, const void* Wo, const void* b_ar, const void* b_f,
    const void* b_r, const void* bo,
    unsigned short* Abf, unsigned short* Bt, unsigned short* Wt,
    float* bias_o, float* bias_px,
    unsigned short* Wrm, unsigned short* wprb, unsigned short* wfmb,
    unsigned short* tile) {
  int t = blockIdx.x, tid = threadIdx.x;
  if (t < 1088) {
    int kt = t % 34, nt = t / 34;
    int k0 = kt * 64, n0 = nt * 64;
    for (int i = tid; i < 64 * 64; i += 256) {
      int kk = i >> 6, nn = i & 63;   // consecutive tid -> consecutive nn (coalesced)
      tile[nn * 66 + kk] = f2bu(ld<BF16>(Wo, (size_t)(k0 + kk) * DOUT + n0 + nn));
    }
    __syncthreads();
    for (int i = tid; i < 64 * 64; i += 256) {
      int nn = i >> 6, kk = i & 63;   // consecutive kk -> coalesced 128B writes
      Bt[(size_t)(n0 + nn) * KT + k0 + kk] = tile[nn * 66 + kk];
    }
  } else if (t < 1216) {
    int bx = t - 1088;
    for (int i = tid; i < 8192; i += 256) {
      int r = bx * 4 + (i >> 11), c = i & 2047;
      Abf[(size_t)r * KT + c] = f2bu(ld<BF16>(x, (size_t)r * DIN + c));
    }
  } else if (t < 1280) {
    int q = t - 1216;
    int k0 = (q >> 1) * 64, j0 = (q & 1) * 65;
    for (int i = tid; i < 64 * 65; i += 256) {
      int kl = i / 65, jl = i % 65;   // consecutive tid -> consecutive jl
      int j = j0 + jl, k = k0 + kl;
      float v;
      if (j < 64)       v = ld<BF16>(W_ar, (size_t)k * 64 + j);
      else if (j == 64) v = ld<BF16>(W_f, k);
      else              v = ld<BF16>(W_r, (size_t)k * 65 + (j - 65));
      tile[jl * 66 + kl] = f2bu(v);
    }
    __syncthreads();
    for (int i = tid; i < 65 * 64; i += 256) {
      int jl = i >> 6, kk = i & 63;
      Wt[(size_t)(j0 + jl) * DIN + k0 + kk] = tile[jl * 66 + kk];
    }
  } else if (t < 1288) {
    int c = (t - 1280) * 256 + tid;
    bias_o[c] = ld<BF16>(bo, c);
  } else if (t == 1288) {
    if (tid < PXW) {
      float v;
      if (tid < 64)       v = ld<BF16>(b_ar, tid);
      else if (tid == 64) v = ld<BF16>(b_f, 0);
      else                v = ld<BF16>(b_r, tid - 65);
      bias_px[tid] = v;
    }
  } else {
    // memory-half weight panel for k_fused's MFMA B-operand
    for (int i = tid; i < 64 * 65; i += 256) {
      int k = i / 65, c = i % 65;   // coalesced read of W_r rows 2048..2111
      tile[c * 66 + k] = f2bu(ld<BF16>(W_r, (size_t)(2048 + k) * 65 + c));
    }
    __syncthreads();
    for (int i = tid; i < 65 * 64; i += 256) {
      int c = i >> 6, k = i & 63;
      Wrm[c * 64 + k] = tile[c * 66 + k];
    }
    if (tid < 64) {
      wprb[tid] = f2bu(ld<BF16>(W_pr, tid));
      wfmb[tid] = f2bu(ld<BF16>(W_f, 2048 + tid));
    }
  }
}

__global__ __launch_bounds__(256) void k_pack(
    const void* __restrict__ x, const void* __restrict__ W_ar,
    const void* __restrict__ W_pr, const void* __restrict__ W_f,
    const void* __restrict__ W_r, const void* __restrict__ Wo,
    const void* __restrict__ b_ar, const void* __restrict__ b_f,
    const void* __restrict__ b_r, const void* __restrict__ bo,
    unsigned short* __restrict__ Abf, unsigned short* __restrict__ Bt,
    unsigned short* __restrict__ Wt, float* __restrict__ bias_o,
    float* __restrict__ bias_px, unsigned short* __restrict__ Wrm,
    unsigned short* __restrict__ wprb, unsigned short* __restrict__ wfmb) {
  __shared__ unsigned short tile[65 * 66];
  if (detect_bf16(x))
    pack_body<true >(x, W_ar, W_pr, W_f, W_r, Wo, b_ar, b_f, b_r, bo,
                     Abf, Bt, Wt, bias_o, bias_px, Wrm, wprb, wfmb, tile);
  else
    pack_body<false>(x, W_ar, W_pr, W_f, W_r, Wo, b_ar, b_f, b_r, bo,
                     Abf, Bt, Wt, bias_o, bias_px, Wrm, wprb, wfmb, tile);
}

// ---------------------------------------------------------------------------
// k_proj_dot: px[b][j] = dot(x[b], Wt[j]) + bias_px[j].  Dtype-free (bf16 ws).
// ---------------------------------------------------------------------------
__global__ __launch_bounds__(256) void k_proj_dot(
    const unsigned short* __restrict__ Abf,
    const unsigned short* __restrict__ Wt,
    const float* __restrict__ bias_px,
    float* __restrict__ px) {
  __shared__ float xs[DIN];
  int b = blockIdx.x;
  for (int k = threadIdx.x; k < DIN; k += 256) xs[k] = bu2f(Abf[(size_t)b * KT + k]);
  __syncthreads();
  int wv = threadIdx.x >> 6, lane = threadIdx.x & 63;
  for (int j = wv; j < PXW; j += 4) {
    const unsigned short* wc = Wt + (size_t)j * DIN;
    float acc = 0.f;
#pragma unroll
    for (int i = 0; i < 4; ++i) {
      int k0 = i * 512 + lane * 8;
      U8x16 t; t.v = *(const uint4*)(wc + k0);
      const float4* xp = (const float4*)&xs[k0];
      float4 xa = xp[0], xb = xp[1];
      acc += xa.x * bu2f(t.u[0]) + xa.y * bu2f(t.u[1])
           + xa.z * bu2f(t.u[2]) + xa.w * bu2f(t.u[3])
           + xb.x * bu2f(t.u[4]) + xb.y * bu2f(t.u[5])
           + xb.z * bu2f(t.u[6]) + xb.w * bu2f(t.u[7]);
    }
#pragma unroll
    for (int off = 32; off; off >>= 1) acc += __shfl_xor(acc, off, 64);
    if (lane == 0) px[b * PXW + j] = acc + bias_px[j];
  }
}

// ---------------------------------------------------------------------------
// k_fused (MFMA version): per batch b, one [128x64]@[64x80] bf16 MFMA matmul
// computes ALL per-slot dots at once. B-panel columns:
//   0: q_hi   1: w_pr   2: w_fm   3..67: w_rm[0..64]   68: q_lo   69..79: 0
// memory & weights are bf16-representable (exact in bf16 MFMA); q (f32 from
// proj GEMM) is carried as hi+lo bf16 split -> f32-grade accuracy.
// Epilogue: wave-shuffle softmaxes, recalls -> Abf tail, gated update -> dout.
// Bp (11.5KB) aliases out_s' first bytes (barrier-separated lifetimes).
// ---------------------------------------------------------------------------
template<bool BF16>
__device__ void fused_body(
    const void* memory, const void* b_pr, const float* px,
    const unsigned short* Wrm, const unsigned short* wprb,
    const unsigned short* wfmb,
    unsigned short* Abf, void* dout,
    unsigned short* mem_bf, float* out_s, float* scr,
    float* sa_s, float* sp_s, float* fg_s, float* r64_s,
    float* pxr_s, float* red) {
  unsigned short* Bp = (unsigned short*)out_s;  // aliased: Bp[80][MS]
  int b = blockIdx.x, tid = threadIdx.x;
  size_t mb = (size_t)b * (NSLOT * DMEM);

  // ---- phase 1: stage memory (bf16, stride MS) + B-panel ----
  for (int i = tid; i < NSLOT * DMEM / 2; i += 256) {
    int n = i >> 5, k2 = (i & 31) << 1;
    float v0, v1;
    if (BF16) {
      unsigned int u = ((const unsigned int*)memory)[(mb >> 1) + (size_t)i];
      v0 = bu2f((unsigned short)u); v1 = bu2f((unsigned short)(u >> 16));
    } else {
      float2 f = ((const float2*)memory)[(mb >> 1) + (size_t)i];
      v0 = f.x; v1 = f.y;
    }
    ((unsigned int*)mem_bf)[(n * MS + k2) >> 1] =
        (unsigned int)f2bu(v0) | ((unsigned int)f2bu(v1) << 16);
  }
  for (int i = tid; i < 65 * 32; i += 256) {             // cols 3..67 <- Wrm
    int c = i >> 5, k2 = (i & 31) << 1;
    ((unsigned int*)Bp)[((3 + c) * MS + k2) >> 1] = ((const unsigned int*)Wrm)[i];
  }
  if (tid < 32) {                                        // cols 0,1,2,68
    int k2 = tid << 1;
    float q0 = px[b * PXW + k2], q1 = px[b * PXW + k2 + 1];
    unsigned short h0 = f2bu(q0), h1 = f2bu(q1);
    unsigned short l0 = f2bu(q0 - bu2f(h0)), l1 = f2bu(q1 - bu2f(h1));
    unsigned int* Bw = (unsigned int*)Bp;
    Bw[(0 * MS + k2) >> 1]  = (unsigned int)h0 | ((unsigned int)h1 << 16);
    Bw[(68 * MS + k2) >> 1] = (unsigned int)l0 | ((unsigned int)l1 << 16);
    Bw[(1 * MS + k2) >> 1]  = ((const unsigned int*)wprb)[tid];
    Bw[(2 * MS + k2) >> 1]  = ((const unsigned int*)wfmb)[tid];
  }
  for (int i = tid; i < 11 * 32; i += 256) {             // cols 69..79 = 0
    int c = 69 + (i >> 5), k2 = (i & 31) << 1;
    ((unsigned int*)Bp)[(c * MS + k2) >> 1] = 0;
  }
  if (tid < 65) pxr_s[tid] = px[b * PXW + 65 + tid];
  __syncthreads();

  // ---- phase 2: MFMA  D[128x80] = mem[128x64] @ B[64x80] ----
  int w = tid >> 6, lane = tid & 63;
  int lr = lane & 15, lk = (lane >> 4) * 8;
  f32x4 acc[2][5] = {};
  const unsigned short* Ab0 = &mem_bf[(w * 32 + lr) * MS + lk];
  const unsigned short* Bb  = &Bp[lr * MS + lk];
#pragma unroll
  for (int ks = 0; ks < 2; ++ks) {
    short8 a0 = *(const short8*)(Ab0 + ks * 32);
    short8 a1 = *(const short8*)(Ab0 + 16 * MS + ks * 32);
#pragma unroll
    for (int ct = 0; ct < 5; ++ct) {
      short8 bf = *(const short8*)(Bb + ct * 16 * MS + ks * 32);
      acc[0][ct] = __builtin_amdgcn_mfma_f32_16x16x32_bf16(a0, bf, acc[0][ct], 0, 0, 0);
      acc[1][ct] = __builtin_amdgcn_mfma_f32_16x16x32_bf16(a1, bf, acc[1][ct], 0, 0, 0);
    }
  }
  __syncthreads();  // all Bp reads done before out_s (aliases Bp) is written

  // ---- phase 3: scatter D to LDS (rem cols -> out_s; special cols -> scr) ----
#pragma unroll
  for (int rt = 0; rt < 2; ++rt) {
    int row0 = w * 32 + rt * 16 + (lane >> 4) * 4;
#pragma unroll
    for (int ct = 0; ct < 5; ++ct) {
      int col = ct * 16 + lr;
#pragma unroll
      for (int r = 0; r < 4; ++r) {
        float v = acc[rt][ct][r];
        int row = row0 + r;
        if (col >= 3 && col < 67)  out_s[row * OS + (col - 3)] = v;
        else if (col == 0)         scr[0 * 128 + row] = v;   // q_hi part
        else if (col == 68)        scr[1 * 128 + row] = v;   // q_lo part
        else if (col == 1)         scr[2 * 128 + row] = v;   // passive
        else if (col == 2)         scr[3 * 128 + row] = v;   // forget
        else if (col == 67)        scr[4 * 128 + row] = v;   // rem[64]
      }
    }
  }
  __syncthreads();

  // ---- phase 4: gates + two softmaxes over 128 slots (wave shuffles) ----
  float pxf = px[b * PXW + 64];
  float bpr = ld<BF16>(b_pr, 0);
  int n = tid & 127;
  float v;
  if (tid < 128) {
    v = scr[0 * 128 + n] + scr[1 * 128 + n];               // active score
    fg_s[n]  = 1.1f / (1.f + __expf(-(scr[3 * 128 + n] + pxf)));
    r64_s[n] = scr[4 * 128 + n] + pxr_s[64];
  } else {
    v = scr[2 * 128 + n] + bpr;                            // passive score
  }
  float mxl = v;
#pragma unroll
  for (int off = 32; off; off >>= 1) mxl = fmaxf(mxl, __shfl_xor(mxl, off, 64));
  if (lane == 0) red[w] = mxl;
  __syncthreads();
  int base = w & 2;
  float mx = fmaxf(red[base], red[base + 1]);
  float e = __expf(v - mx);
  float s = e;
#pragma unroll
  for (int off = 32; off; off >>= 1) s += __shfl_xor(s, off, 64);
  if (lane == 0) red[4 + w] = s;
  __syncthreads();
  float inv = 1.f / (red[4 + base] + red[4 + base + 1]);
  float wt = e * inv;
  if (tid < 128) sa_s[n] = wt; else sp_s[n] = wt;
  __syncthreads();

  // ---- phase 5: recalls -> Abf[b][2048 + 0:128] as bf16 (GEMM A tail) ----
  if (tid < 128) {
    int mcol = tid & 63;
    const float* wv = (tid < 64) ? sa_s : sp_s;
    float acc2 = 0.f;
#pragma unroll 8
    for (int nn = 0; nn < NSLOT; ++nn)
      acc2 += bu2f(mem_bf[nn * MS + mcol]) * wv[nn];
    Abf[(size_t)b * KT + DIN + tid] = f2bu(acc2);
  }

  // ---- phase 6: gated memory update -> dout ----
  size_t obase = (size_t)NB * DOUT + mb;
  for (int i = tid; i < NSLOT * DMEM; i += 256) {
    int nn = i >> 6, j = i & 63;
    float mv  = bu2f(mem_bf[nn * MS + j]);
    float rem = out_s[nn * OS + j] + pxr_s[j];
    st<BF16>(dout, obase + i, mv * fg_s[nn] + r64_s[nn] * rem);
  }
}

__global__ __launch_bounds__(256) void k_fused(
    const void* __restrict__ x, const void* __restrict__ memory,
    const void* __restrict__ b_pr, const float* __restrict__ px,
    const unsigned short* __restrict__ Wrm,
    const unsigned short* __restrict__ wprb,
    const unsigned short* __restrict__ wfmb,
    unsigned short* __restrict__ Abf, void* __restrict__ dout) {
  __shared__ __align__(16) unsigned short mem_bf[NSLOT * MS];  // 18.4 KB
  __shared__ __align__(16) float out_s[NSLOT * OS];            // 34.8 KB (Bp aliased)
  __shared__ float scr[5 * 128];
  __shared__ float sa_s[128], sp_s[128], fg_s[128], r64_s[128];
  __shared__ float pxr_s[65];
  __shared__ float red[8];
  if (detect_bf16(x))
    fused_body<true >(memory, b_pr, px, Wrm, wprb, wfmb, Abf, dout,
                      mem_bf, out_s, scr, sa_s, sp_s, fg_s, r64_s, pxr_s, red);
  else
    fused_body<false>(memory, b_pr, px, Wrm, wprb, wfmb, Abf, dout,
                      mem_bf, out_s, scr, sa_s, sp_s, fg_s, r64_s, pxr_s, red);
}

// ---------------------------------------------------------------------------
// k_gemm: output = Abf @ Bt^T + bias_o, barrier-free wave tiling.
// 256 blocks x 4 waves; wave tile 16 rows x 64 cols; fragments loaded
// global->register (16B/lane), one-tile register prefetch, no LDS.
// Fragment layouts (m89/m91 + verified in R5-R7): A/B: m|n=lane&15,
// k=(lane>>4)*8+j ; D: col=lane&15, row=(lane>>4)*4+reg.
// ---------------------------------------------------------------------------
template<bool BF16>
__device__ void gemm_body(const unsigned short* Abf, const unsigned short* Bt,
                          const float* bias_o, void* dout) {
  int tid = threadIdx.x;
  int lane = tid & 63, w = tid >> 6;
  int bc = blockIdx.x & 31, br = blockIdx.x >> 5;
  int col0 = bc * 64, row0 = br * 64 + w * 16;
  int lr = lane & 15, lk = (lane >> 4) * 8;

  const unsigned short* Ap = Abf + (size_t)(row0 + lr) * KT + lk;
  const unsigned short* Bp = Bt  + (size_t)(col0 + lr) * KT + lk;

  f32x4 acc0 = {}, acc1 = {}, acc2 = {}, acc3 = {};
  short8 ac  = *(const short8*)Ap;
  short8 bc0 = *(const short8*)(Bp);
  short8 bc1 = *(const short8*)(Bp + 16 * KT);
  short8 bc2 = *(const short8*)(Bp + 32 * KT);
  short8 bc3 = *(const short8*)(Bp + 48 * KT);

  for (int i = 0; i < NK; ++i) {
    short8 an = {}, bn0 = {}, bn1 = {}, bn2 = {}, bn3 = {};
    if (i + 1 < NK) {
      int k = (i + 1) * 32;
      an  = *(const short8*)(Ap + k);
      bn0 = *(const short8*)(Bp + k);
      bn1 = *(const short8*)(Bp + 16 * KT + k);
      bn2 = *(const short8*)(Bp + 32 * KT + k);
      bn3 = *(const short8*)(Bp + 48 * KT + k);
    }
    acc0 = __builtin_amdgcn_mfma_f32_16x16x32_bf16(ac, bc0, acc0, 0, 0, 0);
    acc1 = __builtin_amdgcn_mfma_f32_16x16x32_bf16(ac, bc1, acc1, 0, 0, 0);
    acc2 = __builtin_amdgcn_mfma_f32_16x16x32_bf16(ac, bc2, acc2, 0, 0, 0);
    acc3 = __builtin_amdgcn_mfma_f32_16x16x32_bf16(ac, bc3, acc3, 0, 0, 0);
    ac = an; bc0 = bn0; bc1 = bn1; bc2 = bn2; bc3 = bn3;
  }

  int rbase = row0 + (lane >> 4) * 4;
  f32x4 accs[4] = {acc0, acc1, acc2, acc3};
#pragma unroll
  for (int j = 0; j < 4; ++j) {
    int c = col0 + j * 16 + lr;
    float bias = bias_o[c];
#pragma unroll
    for (int r = 0; r < 4; ++r)
      st<BF16>(dout, (size_t)(rbase + r) * DOUT + c, accs[j][r] + bias);
  }
}

__global__ __launch_bounds__(256) void k_gemm(
    const void* __restrict__ x,
    const unsigned short* __restrict__ Abf,
    const unsigned short* __restrict__ Bt,
    const float* __restrict__ bias_o, void* __restrict__ dout) {
  if (detect_bf16(x)) gemm_body<true >(Abf, Bt, bias_o, dout);
  else                gemm_body<false>(Abf, Bt, bias_o, dout);
}

// ---------------------------------------------------------------------------
extern "C" void kernel_launch(void* const* d_in, const int* in_sizes, int n_in,
                              void* d_out, int out_size, void* d_ws, size_t ws_size,
                              hipStream_t stream) {
  const void* x    = d_in[0];
  const void* mem  = d_in[1];
  const void* W_ar = d_in[2];
  const void* b_ar = d_in[3];
  const void* W_pr = d_in[4];
  const void* b_pr = d_in[5];
  const void* W_f  = d_in[6];
  const void* b_f  = d_in[7];
  const void* W_r  = d_in[8];
  const void* b_r  = d_in[9];
  const void* W_o  = d_in[10];
  const void* b_o  = d_in[11];

  unsigned short* Abf    = (unsigned short*)d_ws;          // 512*2176
  unsigned short* Bt     = Abf + (size_t)NB * KT;          // 2048*2176
  unsigned short* Wt     = Bt + (size_t)DOUT * KT;         // 130*2048
  float*          bias_o = (float*)(Wt + PXW * DIN);       // 2048
  float*          bias_px= bias_o + DOUT;                  // 130 (+pad)
  float*          px     = bias_px + 132;                  // 512*130
  unsigned short* Wrm    = (unsigned short*)(px + NB * PXW); // 65*64
  unsigned short* wprb   = Wrm + 65 * 64;                  // 64
  unsigned short* wfmb   = wprb + 64;                      // 64

  k_pack<<<1290, 256, 0, stream>>>(x, W_ar, W_pr, W_f, W_r, W_o, b_ar, b_f,
                                   b_r, b_o, Abf, Bt, Wt, bias_o, bias_px,
                                   Wrm, wprb, wfmb);
  k_proj_dot<<<NB, 256, 0, stream>>>(Abf, Wt, bias_px, px);
  k_fused<<<NB, 256, 0, stream>>>(x, mem, b_pr, px, Wrm, wprb, wfmb, Abf, d_out);
  k_gemm<<<256, 256, 0, stream>>>(x, Abf, Bt, bias_o, d_out);
}

// Round 2
// 154.749 us; speedup vs baseline: 1.2653x; 1.2209x over previous
//
#include <hip/hip_runtime.h>
#include <hip/hip_bf16.h>

// Problem: B=512, N_SLOTS=128, IN=2048, MEM=64, OUT=2048.
// Dtype self-detection: each wave ballots on x's bit patterns (fp32 buffers
// holding bf16-quantized values, per R4-R7 evidence; bf16 world also handled).
// Pipeline (4 dispatches): k_pack (bf16-pack A/x, Wo^T, proj weights, biases,
// transposed W_r-mem/W_pr/W_f-tail panel) -> k_proj (NOW split-K MFMA GEMM,
// 4 partials) -> k_fused (MFMA scores/softmax/recalls/mem-update) -> k_gemm
// (NOW LDS-staged B with XOR swizzle + XCD-aware block swizzle).
// d_out = [output (512*2048) | new_memory (512*128*64)], input dtype.

#define NB    512
#define NSLOT 128
#define DIN   2048
#define DMEM  64
#define DOUT  2048
#define PXW   130              // 64 (q) + 1 (forget) + 65 (remember)
#define KT    (DIN + 2 * DMEM) // 2176 = GEMM K and packed row stride
#define MS    72               // mem_bf / Bp row stride in bf16 (2-way-free banks)
#define OS    68               // out_s row stride in f32
#define PXP   132              // px partial row stride (f32)
#define PXCH  (NB * PXP)       // px partial chunk stride

typedef __hip_bfloat16 bf16;
typedef __attribute__((ext_vector_type(8))) short short8;
typedef __attribute__((ext_vector_type(4))) float f32x4;

template<bool BF16>
__device__ __forceinline__ float ld(const void* p, size_t i) {
  if (BF16) return __bfloat162float(((const bf16*)p)[i]);
  return ((const float*)p)[i];
}
template<bool BF16>
__device__ __forceinline__ void st(void* p, size_t i, float v) {
  if (BF16) ((bf16*)p)[i] = __float2bfloat16(v);
  else      ((float*)p)[i] = v;
}
// f32 -> bf16 bits (RNE); bf16 bits -> f32 (exact).
__device__ __forceinline__ unsigned short f2bu(float f) {
  unsigned int u = __builtin_bit_cast(unsigned int, f);
  u = (u + 0x7FFFu + ((u >> 16) & 1u)) >> 16;
  return (unsigned short)u;
}
__device__ __forceinline__ float bu2f(unsigned short u) {
  unsigned int w = ((unsigned int)u) << 16;
  return __builtin_bit_cast(float, w);
}

// Wave-level dtype detect (see R0 notes): identical verdict on all waves.
__device__ __forceinline__ bool detect_bf16(const void* x) {
  const unsigned short* u = (const unsigned short*)x;
  int lane = threadIdx.x & 63;
  unsigned short v = u[lane * 2048];
  int e = (v >> 7) & 0xFF;
  unsigned long long m = __ballot(e >= 100 && e <= 140);
  return __popcll(m) > 32;
}

union U8x16 { uint4 v; unsigned short u[8]; };

// 16B global -> LDS direct (wave-uniform LDS base + lane*16; global per-lane).
__device__ __forceinline__ void gload16(const void* g, void* l) {
  __builtin_amdgcn_global_load_lds(
      (const __attribute__((address_space(1))) unsigned int*)g,
      (__attribute__((address_space(3))) unsigned int*)l, 16, 0, 0);
}

// sum of 4 split-K px partials
__device__ __forceinline__ float px4(const float* pxp, int b, int j) {
  const float* p = pxp + (size_t)b * PXP + j;
  return p[0] + p[PXCH] + p[2 * PXCH] + p[3 * PXCH];
}

// ---------------------------------------------------------------------------
// k_pack: one dispatch, block ranges:
//  [0,1088)   : Bt[n][k] = Wo[k][n] bf16   (34 k-tiles x 32 n-tiles, LDS transpose)
//  [1088,1216): Abf[b][0:2048] = x bf16    (4 rows/block)
//  [1216,1280): Wt[j][k] = proj-weight col j (LDS transpose, 65-col halves)
//  [1280,1288): bias_o[2048] f32
//  [1288]     : bias_px[130] f32
//  [1289]     : Wrm[c][k] = W_r[2048+k][c] bf16 (65x64), wprb/wfmb bf16[64]
// ---------------------------------------------------------------------------
template<bool BF16>
__device__ void pack_body(
    const void* x, const void* W_ar, const void* W_pr, const void* W_f,
    const void* W_r, const void* Wo, const void* b_ar, const void* b_f,
    const void* b_r, const void* bo,
    unsigned short* Abf, unsigned short* Bt, unsigned short* Wt,
    float* bias_o, float* bias_px,
    unsigned short* Wrm, unsigned short* wprb, unsigned short* wfmb,
    unsigned short* tile) {
  int t = blockIdx.x, tid = threadIdx.x;
  if (t < 1088) {
    int kt = t % 34, nt = t / 34;
    int k0 = kt * 64, n0 = nt * 64;
    for (int i = tid; i < 64 * 64; i += 256) {
      int kk = i >> 6, nn = i & 63;   // consecutive tid -> consecutive nn (coalesced)
      tile[nn * 66 + kk] = f2bu(ld<BF16>(Wo, (size_t)(k0 + kk) * DOUT + n0 + nn));
    }
    __syncthreads();
    for (int i = tid; i < 64 * 64; i += 256) {
      int nn = i >> 6, kk = i & 63;   // consecutive kk -> coalesced 128B writes
      Bt[(size_t)(n0 + nn) * KT + k0 + kk] = tile[nn * 66 + kk];
    }
  } else if (t < 1216) {
    int bx = t - 1088;
    for (int i = tid; i < 8192; i += 256) {
      int r = bx * 4 + (i >> 11), c = i & 2047;
      Abf[(size_t)r * KT + c] = f2bu(ld<BF16>(x, (size_t)r * DIN + c));
    }
  } else if (t < 1280) {
    int q = t - 1216;
    int k0 = (q >> 1) * 64, j0 = (q & 1) * 65;
    for (int i = tid; i < 64 * 65; i += 256) {
      int kl = i / 65, jl = i % 65;   // consecutive tid -> consecutive jl
      int j = j0 + jl, k = k0 + kl;
      float v;
      if (j < 64)       v = ld<BF16>(W_ar, (size_t)k * 64 + j);
      else if (j == 64) v = ld<BF16>(W_f, k);
      else              v = ld<BF16>(W_r, (size_t)k * 65 + (j - 65));
      tile[jl * 66 + kl] = f2bu(v);
    }
    __syncthreads();
    for (int i = tid; i < 65 * 64; i += 256) {
      int jl = i >> 6, kk = i & 63;
      Wt[(size_t)(j0 + jl) * DIN + k0 + kk] = tile[jl * 66 + kk];
    }
  } else if (t < 1288) {
    int c = (t - 1280) * 256 + tid;
    bias_o[c] = ld<BF16>(bo, c);
  } else if (t == 1288) {
    if (tid < PXW) {
      float v;
      if (tid < 64)       v = ld<BF16>(b_ar, tid);
      else if (tid == 64) v = ld<BF16>(b_f, 0);
      else                v = ld<BF16>(b_r, tid - 65);
      bias_px[tid] = v;
    }
  } else {
    // memory-half weight panel for k_fused's MFMA B-operand
    for (int i = tid; i < 64 * 65; i += 256) {
      int k = i / 65, c = i % 65;   // coalesced read of W_r rows 2048..2111
      tile[c * 66 + k] = f2bu(ld<BF16>(W_r, (size_t)(2048 + k) * 65 + c));
    }
    __syncthreads();
    for (int i = tid; i < 65 * 64; i += 256) {
      int c = i >> 6, k = i & 63;
      Wrm[c * 64 + k] = tile[c * 66 + k];
    }
    if (tid < 64) {
      wprb[tid] = f2bu(ld<BF16>(W_pr, tid));
      wfmb[tid] = f2bu(ld<BF16>(W_f, 2048 + tid));
    }
  }
}

__global__ __launch_bounds__(256) void k_pack(
    const void* __restrict__ x, const void* __restrict__ W_ar,
    const void* __restrict__ W_pr, const void* __restrict__ W_f,
    const void* __restrict__ W_r, const void* __restrict__ Wo,
    const void* __restrict__ b_ar, const void* __restrict__ b_f,
    const void* __restrict__ b_r, const void* __restrict__ bo,
    unsigned short* __restrict__ Abf, unsigned short* __restrict__ Bt,
    unsigned short* __restrict__ Wt, float* __restrict__ bias_o,
    float* __restrict__ bias_px, unsigned short* __restrict__ Wrm,
    unsigned short* __restrict__ wprb, unsigned short* __restrict__ wfmb) {
  __shared__ unsigned short tile[65 * 66];
  if (detect_bf16(x))
    pack_body<true >(x, W_ar, W_pr, W_f, W_r, Wo, b_ar, b_f, b_r, bo,
                     Abf, Bt, Wt, bias_o, bias_px, Wrm, wprb, wfmb, tile);
  else
    pack_body<false>(x, W_ar, W_pr, W_f, W_r, Wo, b_ar, b_f, b_r, bo,
                     Abf, Bt, Wt, bias_o, bias_px, Wrm, wprb, wfmb, tile);
}

// ---------------------------------------------------------------------------
// k_proj: split-K MFMA GEMM. pxp[ks][b][j] = Abf[b, ks*512:(ks+1)*512] @
// Wt[j, same]^T (+bias at ks==0). 1152 waves = 32 row-tiles x 9 j-tiles x 4 K.
// Dtype-free (bf16 workspace). Fragment layouts as k_gemm (verified R5-R7).
// ---------------------------------------------------------------------------
__global__ __launch_bounds__(128) void k_proj(
    const unsigned short* __restrict__ Abf,
    const unsigned short* __restrict__ Wt,
    const float* __restrict__ bias_px,
    float* __restrict__ pxp) {
  int wid = blockIdx.x * 2 + (threadIdx.x >> 6);
  int lane = threadIdx.x & 63, lr = lane & 15, lk = (lane >> 4) * 8;
  int ks = wid & 3;
  int tt = wid >> 2;            // 0..287
  int jt = tt % 9, rt = tt / 9;
  int brow = rt * 16, j0 = jt * 16, k0 = ks * 512;
  const unsigned short* Ap = Abf + (size_t)(brow + lr) * KT + k0 + lk;
  const unsigned short* Bp = Wt + (size_t)(j0 + lr) * DIN + k0 + lk;
  // note: j-tile 8 reads Wt rows 130..143 -> garbage inside ws (never stored)
  f32x4 acc = {};
  short8 a0 = *(const short8*)Ap;
  short8 b0 = *(const short8*)Bp;
  short8 a1 = *(const short8*)(Ap + 32);
  short8 b1 = *(const short8*)(Bp + 32);
  for (int i = 0; i < 16; ++i) {
    short8 a2 = {}, b2 = {};
    if (i + 2 < 16) {
      a2 = *(const short8*)(Ap + (i + 2) * 32);
      b2 = *(const short8*)(Bp + (i + 2) * 32);
    }
    acc = __builtin_amdgcn_mfma_f32_16x16x32_bf16(a0, b0, acc, 0, 0, 0);
    a0 = a1; b0 = b1; a1 = a2; b1 = b2;
  }
  int j = j0 + lr;
  if (j < PXW) {
    float bias = (ks == 0) ? bias_px[j] : 0.f;
    int r0 = brow + ((lane >> 4) << 2);
#pragma unroll
    for (int r = 0; r < 4; ++r)
      pxp[(size_t)ks * PXCH + (size_t)(r0 + r) * PXP + j] = acc[r] + bias;
  }
}

// ---------------------------------------------------------------------------
// k_fused (MFMA version): per batch b, one [128x64]@[64x80] bf16 MFMA matmul
// computes ALL per-slot dots at once. B-panel columns:
//   0: q_hi   1: w_pr   2: w_fm   3..67: w_rm[0..64]   68: q_lo   69..79: 0
// q (f32 from split-K proj) carried as hi+lo bf16 -> f32-grade accuracy.
// Epilogue: wave-shuffle softmaxes, recalls -> Abf tail, gated update -> dout.
// Bp (11.5KB) aliases out_s' first bytes (barrier-separated lifetimes).
// ---------------------------------------------------------------------------
template<bool BF16>
__device__ void fused_body(
    const void* memory, const void* b_pr, const float* pxp,
    const unsigned short* Wrm, const unsigned short* wprb,
    const unsigned short* wfmb,
    unsigned short* Abf, void* dout,
    unsigned short* mem_bf, float* out_s, float* scr,
    float* sa_s, float* sp_s, float* fg_s, float* r64_s,
    float* pxr_s, float* red) {
  unsigned short* Bp = (unsigned short*)out_s;  // aliased: Bp[80][MS]
  int b = blockIdx.x, tid = threadIdx.x;
  size_t mb = (size_t)b * (NSLOT * DMEM);

  // ---- phase 1: stage memory (bf16, stride MS) + B-panel ----
  for (int i = tid; i < NSLOT * DMEM / 2; i += 256) {
    int n = i >> 5, k2 = (i & 31) << 1;
    float v0, v1;
    if (BF16) {
      unsigned int u = ((const unsigned int*)memory)[(mb >> 1) + (size_t)i];
      v0 = bu2f((unsigned short)u); v1 = bu2f((unsigned short)(u >> 16));
    } else {
      float2 f = ((const float2*)memory)[(mb >> 1) + (size_t)i];
      v0 = f.x; v1 = f.y;
    }
    ((unsigned int*)mem_bf)[(n * MS + k2) >> 1] =
        (unsigned int)f2bu(v0) | ((unsigned int)f2bu(v1) << 16);
  }
  for (int i = tid; i < 65 * 32; i += 256) {             // cols 3..67 <- Wrm
    int c = i >> 5, k2 = (i & 31) << 1;
    ((unsigned int*)Bp)[((3 + c) * MS + k2) >> 1] = ((const unsigned int*)Wrm)[i];
  }
  if (tid < 32) {                                        // cols 0,1,2,68
    int k2 = tid << 1;
    float q0 = px4(pxp, b, k2), q1 = px4(pxp, b, k2 + 1);
    unsigned short h0 = f2bu(q0), h1 = f2bu(q1);
    unsigned short l0 = f2bu(q0 - bu2f(h0)), l1 = f2bu(q1 - bu2f(h1));
    unsigned int* Bw = (unsigned int*)Bp;
    Bw[(0 * MS + k2) >> 1]  = (unsigned int)h0 | ((unsigned int)h1 << 16);
    Bw[(68 * MS + k2) >> 1] = (unsigned int)l0 | ((unsigned int)l1 << 16);
    Bw[(1 * MS + k2) >> 1]  = ((const unsigned int*)wprb)[tid];
    Bw[(2 * MS + k2) >> 1]  = ((const unsigned int*)wfmb)[tid];
  }
  for (int i = tid; i < 11 * 32; i += 256) {             // cols 69..79 = 0
    int c = 69 + (i >> 5), k2 = (i & 31) << 1;
    ((unsigned int*)Bp)[(c * MS + k2) >> 1] = 0;
  }
  if (tid < 65) pxr_s[tid] = px4(pxp, b, 65 + tid);
  __syncthreads();

  // ---- phase 2: MFMA  D[128x80] = mem[128x64] @ B[64x80] ----
  int w = tid >> 6, lane = tid & 63;
  int lr = lane & 15, lk = (lane >> 4) * 8;
  f32x4 acc[2][5] = {};
  const unsigned short* Ab0 = &mem_bf[(w * 32 + lr) * MS + lk];
  const unsigned short* Bb  = &Bp[lr * MS + lk];
#pragma unroll
  for (int ks = 0; ks < 2; ++ks) {
    short8 a0 = *(const short8*)(Ab0 + ks * 32);
    short8 a1 = *(const short8*)(Ab0 + 16 * MS + ks * 32);
#pragma unroll
    for (int ct = 0; ct < 5; ++ct) {
      short8 bf = *(const short8*)(Bb + ct * 16 * MS + ks * 32);
      acc[0][ct] = __builtin_amdgcn_mfma_f32_16x16x32_bf16(a0, bf, acc[0][ct], 0, 0, 0);
      acc[1][ct] = __builtin_amdgcn_mfma_f32_16x16x32_bf16(a1, bf, acc[1][ct], 0, 0, 0);
    }
  }
  __syncthreads();  // all Bp reads done before out_s (aliases Bp) is written

  // ---- phase 3: scatter D to LDS (rem cols -> out_s; special cols -> scr) ----
#pragma unroll
  for (int rt = 0; rt < 2; ++rt) {
    int row0 = w * 32 + rt * 16 + (lane >> 4) * 4;
#pragma unroll
    for (int ct = 0; ct < 5; ++ct) {
      int col = ct * 16 + lr;
#pragma unroll
      for (int r = 0; r < 4; ++r) {
        float v = acc[rt][ct][r];
        int row = row0 + r;
        if (col >= 3 && col < 67)  out_s[row * OS + (col - 3)] = v;
        else if (col == 0)         scr[0 * 128 + row] = v;   // q_hi part
        else if (col == 68)        scr[1 * 128 + row] = v;   // q_lo part
        else if (col == 1)         scr[2 * 128 + row] = v;   // passive
        else if (col == 2)         scr[3 * 128 + row] = v;   // forget
        else if (col == 67)        scr[4 * 128 + row] = v;   // rem[64]
      }
    }
  }
  __syncthreads();

  // ---- phase 4: gates + two softmaxes over 128 slots (wave shuffles) ----
  float pxf = px4(pxp, b, 64);
  float bpr = ld<BF16>(b_pr, 0);
  int n = tid & 127;
  float v;
  if (tid < 128) {
    v = scr[0 * 128 + n] + scr[1 * 128 + n];               // active score
    fg_s[n]  = 1.1f / (1.f + __expf(-(scr[3 * 128 + n] + pxf)));
    r64_s[n] = scr[4 * 128 + n] + pxr_s[64];
  } else {
    v = scr[2 * 128 + n] + bpr;                            // passive score
  }
  float mxl = v;
#pragma unroll
  for (int off = 32; off; off >>= 1) mxl = fmaxf(mxl, __shfl_xor(mxl, off, 64));
  if (lane == 0) red[w] = mxl;
  __syncthreads();
  int base = w & 2;
  float mx = fmaxf(red[base], red[base + 1]);
  float e = __expf(v - mx);
  float s = e;
#pragma unroll
  for (int off = 32; off; off >>= 1) s += __shfl_xor(s, off, 64);
  if (lane == 0) red[4 + w] = s;
  __syncthreads();
  float inv = 1.f / (red[4 + base] + red[4 + base + 1]);
  float wt = e * inv;
  if (tid < 128) sa_s[n] = wt; else sp_s[n] = wt;
  __syncthreads();

  // ---- phase 5: recalls -> Abf[b][2048 + 0:128] as bf16 (GEMM A tail) ----
  if (tid < 128) {
    int mcol = tid & 63;
    const float* wv = (tid < 64) ? sa_s : sp_s;
    float acc2 = 0.f;
#pragma unroll 8
    for (int nn = 0; nn < NSLOT; ++nn)
      acc2 += bu2f(mem_bf[nn * MS + mcol]) * wv[nn];
    Abf[(size_t)b * KT + DIN + tid] = f2bu(acc2);
  }

  // ---- phase 6: gated memory update -> dout ----
  size_t obase = (size_t)NB * DOUT + mb;
  for (int i = tid; i < NSLOT * DMEM; i += 256) {
    int nn = i >> 6, j = i & 63;
    float mv  = bu2f(mem_bf[nn * MS + j]);
    float rem = out_s[nn * OS + j] + pxr_s[j];
    st<BF16>(dout, obase + i, mv * fg_s[nn] + r64_s[nn] * rem);
  }
}

__global__ __launch_bounds__(256) void k_fused(
    const void* __restrict__ x, const void* __restrict__ memory,
    const void* __restrict__ b_pr, const float* __restrict__ pxp,
    const unsigned short* __restrict__ Wrm,
    const unsigned short* __restrict__ wprb,
    const unsigned short* __restrict__ wfmb,
    unsigned short* __restrict__ Abf, void* __restrict__ dout) {
  __shared__ __align__(16) unsigned short mem_bf[NSLOT * MS];  // 18.4 KB
  __shared__ __align__(16) float out_s[NSLOT * OS];            // 34.8 KB (Bp aliased)
  __shared__ float scr[5 * 128];
  __shared__ float sa_s[128], sp_s[128], fg_s[128], r64_s[128];
  __shared__ float pxr_s[65];
  __shared__ float red[8];
  if (detect_bf16(x))
    fused_body<true >(memory, b_pr, pxp, Wrm, wprb, wfmb, Abf, dout,
                      mem_bf, out_s, scr, sa_s, sp_s, fg_s, r64_s, pxr_s, red);
  else
    fused_body<false>(memory, b_pr, pxp, Wrm, wprb, wfmb, Abf, dout,
                      mem_bf, out_s, scr, sa_s, sp_s, fg_s, r64_s, pxr_s, red);
}

// ---------------------------------------------------------------------------
// k_gemm: output = Abf @ Bt^T + bias_o. 256 blocks x 4 waves, block tile
// 64x64, wave tile 16x64. B staged in LDS via global_load_lds (dbuf, K-step
// 64) and shared by all 4 waves -> L2 traffic 285->71 MB. XOR swizzle on 16B
// units (u ^= c&7) applied on the GLOBAL source (linear LDS dest, rule #21)
// and on ds_read addresses -> 2-way banks (free). A stays reg-prefetched
// (rows distinct per wave, no redundancy). XCD swizzle: blocks on XCD x
// cover col-tiles [4x,4x+4) -> per-XCD L2 set 1.1MB Bt + 2.2MB Abf.
// Fragment layouts (m89/m91 + verified R5-R7): A/B: m|n=lane&15,
// k=(lane>>4)*8+j ; D: col=lane&15, row=(lane>>4)*4+reg.
// ---------------------------------------------------------------------------
__device__ __forceinline__ void stage_b(const unsigned short* src,  // Bt + col0*KT + k0
                                        unsigned short* lds,        // buffer base
                                        int w, int lane) {
#pragma unroll
  for (int q = 0; q < 2; ++q) {
    int c = w * 16 + q * 8 + (lane >> 3);
    int u = lane & 7;
    const unsigned short* gp = src + (size_t)c * KT + ((u ^ (c & 7)) << 3);
    unsigned short* lp = lds + w * 1024 + q * 512;   // wave-uniform base
    gload16(gp, lp);
  }
}

template<bool BF16>
__device__ void gemm_body(const unsigned short* Abf, const unsigned short* Bt,
                          const float* bias_o, void* dout,
                          unsigned short (*Bs)[64 * 64]) {
  int tid = threadIdx.x, lane = tid & 63, w = tid >> 6;
  int bid = blockIdx.x;
  int ct = (bid & 7) * 4 + ((bid >> 3) & 3);   // col tile 0..31 (XCD-grouped)
  int rt = bid >> 5;                           // row tile 0..7
  int col0 = ct * 64, row0 = rt * 64 + w * 16;
  int lr = lane & 15, lk = (lane >> 4) * 8;

  const unsigned short* Ap = Abf + (size_t)(row0 + lr) * KT + lk;
  const unsigned short* Bg = Bt + (size_t)col0 * KT;

  stage_b(Bg, &Bs[0][0], w, lane);
  short8 a0 = *(const short8*)Ap;
  short8 a1 = *(const short8*)(Ap + 32);
  __syncthreads();   // drains stage(0)

  f32x4 acc0 = {}, acc1 = {}, acc2 = {}, acc3 = {};
  int kb0 = ((lk * 2) ^ ((lr & 7) << 4)) >> 1;        // ks=0 ushort offset in row
  int kb1 = ((64 + lk * 2) ^ ((lr & 7) << 4)) >> 1;   // ks=1

  for (int i = 0; i < 34; ++i) {
    if (i + 1 < 34) stage_b(Bg + (i + 1) * 64, &Bs[(i + 1) & 1][0], w, lane);
    short8 an0 = {}, an1 = {};
    if (i + 1 < 34) {
      an0 = *(const short8*)(Ap + (i + 1) * 64);
      an1 = *(const short8*)(Ap + (i + 1) * 64 + 32);
    }
    const unsigned short* bp = &Bs[i & 1][lr * 64];
    short8 b00 = *(const short8*)(bp + 0 * 1024 + kb0);
    short8 b01 = *(const short8*)(bp + 0 * 1024 + kb1);
    short8 b10 = *(const short8*)(bp + 1 * 1024 + kb0);
    short8 b11 = *(const short8*)(bp + 1 * 1024 + kb1);
    short8 b20 = *(const short8*)(bp + 2 * 1024 + kb0);
    short8 b21 = *(const short8*)(bp + 2 * 1024 + kb1);
    short8 b30 = *(const short8*)(bp + 3 * 1024 + kb0);
    short8 b31 = *(const short8*)(bp + 3 * 1024 + kb1);
    acc0 = __builtin_amdgcn_mfma_f32_16x16x32_bf16(a0, b00, acc0, 0, 0, 0);
    acc1 = __builtin_amdgcn_mfma_f32_16x16x32_bf16(a0, b10, acc1, 0, 0, 0);
    acc2 = __builtin_amdgcn_mfma_f32_16x16x32_bf16(a0, b20, acc2, 0, 0, 0);
    acc3 = __builtin_amdgcn_mfma_f32_16x16x32_bf16(a0, b30, acc3, 0, 0, 0);
    acc0 = __builtin_amdgcn_mfma_f32_16x16x32_bf16(a1, b01, acc0, 0, 0, 0);
    acc1 = __builtin_amdgcn_mfma_f32_16x16x32_bf16(a1, b11, acc1, 0, 0, 0);
    acc2 = __builtin_amdgcn_mfma_f32_16x16x32_bf16(a1, b21, acc2, 0, 0, 0);
    acc3 = __builtin_amdgcn_mfma_f32_16x16x32_bf16(a1, b31, acc3, 0, 0, 0);
    __syncthreads();   // stage(i+1) drained; buf[i&1] reads complete chip-wide
    a0 = an0; a1 = an1;
  }

  int rbase = row0 + (lane >> 4) * 4;
  f32x4 accs[4] = {acc0, acc1, acc2, acc3};
#pragma unroll
  for (int j = 0; j < 4; ++j) {
    int c = col0 + j * 16 + lr;
    float bias = bias_o[c];
#pragma unroll
    for (int r = 0; r < 4; ++r)
      st<BF16>(dout, (size_t)(rbase + r) * DOUT + c, accs[j][r] + bias);
  }
}

__global__ __launch_bounds__(256) void k_gemm(
    const void* __restrict__ x,
    const unsigned short* __restrict__ Abf,
    const unsigned short* __restrict__ Bt,
    const float* __restrict__ bias_o, void* __restrict__ dout) {
  __shared__ __align__(16) unsigned short Bs[2][64 * 64];   // 16 KB dbuf
  if (detect_bf16(x)) gemm_body<true >(Abf, Bt, bias_o, dout, Bs);
  else                gemm_body<false>(Abf, Bt, bias_o, dout, Bs);
}

// ---------------------------------------------------------------------------
extern "C" void kernel_launch(void* const* d_in, const int* in_sizes, int n_in,
                              void* d_out, int out_size, void* d_ws, size_t ws_size,
                              hipStream_t stream) {
  const void* x    = d_in[0];
  const void* mem  = d_in[1];
  const void* W_ar = d_in[2];
  const void* b_ar = d_in[3];
  const void* W_pr = d_in[4];
  const void* b_pr = d_in[5];
  const void* W_f  = d_in[6];
  const void* b_f  = d_in[7];
  const void* W_r  = d_in[8];
  const void* b_r  = d_in[9];
  const void* W_o  = d_in[10];
  const void* b_o  = d_in[11];

  unsigned short* Abf    = (unsigned short*)d_ws;            // 512*2176
  unsigned short* Bt     = Abf + (size_t)NB * KT;            // 2048*2176
  unsigned short* Wt     = Bt + (size_t)DOUT * KT;           // 130*2048
  float*          bias_o = (float*)(Wt + PXW * DIN);         // 2048
  float*          bias_px= bias_o + DOUT;                    // 132 (padded)
  float*          pxp    = bias_px + 132;                    // 4*512*132
  unsigned short* Wrm    = (unsigned short*)(pxp + 4 * PXCH); // 65*64
  unsigned short* wprb   = Wrm + 65 * 64;                    // 64
  unsigned short* wfmb   = wprb + 64;                        // 64

  k_pack<<<1290, 256, 0, stream>>>(x, W_ar, W_pr, W_f, W_r, W_o, b_ar, b_f,
                                   b_r, b_o, Abf, Bt, Wt, bias_o, bias_px,
                                   Wrm, wprb, wfmb);
  k_proj<<<576, 128, 0, stream>>>(Abf, Wt, bias_px, pxp);
  k_fused<<<NB, 256, 0, stream>>>(x, mem, b_pr, pxp, Wrm, wprb, wfmb, Abf, d_out);
  k_gemm<<<256, 256, 0, stream>>>(x, Abf, Bt, bias_o, d_out);
}